// Round 7
// baseline (241.976 us; speedup 1.0000x reference)
//
#include <hip/hip_runtime.h>
#include <hip/hip_bf16.h>

// SegmentConv2d: fake-quant-int8 (global for x, per-128-oc-chunk for w) + 3x3 pad1 conv + bias.
// int8 path: quantize to real int8, conv with mfma_i32_16x16x64_i8 (exact int accum),
// scale+bias epilogue.
//
// Shapes: x[8][256][128][128] f32, w[512][256][3][3] f32, bias[512], out[8][512][128][128] f32.
//
// ws layout:
//   [0..63]           : amax[5] (uint bits, written by k_amax2 - no atomics)
//   [64..79]          : 16B zeros (OOB redirect for global_load_lds)
//   [256..13567]      : per-block amax partials float[3328] (x: 0..2047, w: 2048..3199)
//   [16384..)         : qx int8 NHWC  [n][h][w][c]  = 33,554,432 B
//   [16384+32M..)     : qw int8       [r*3+s][oc][c] = 1,179,648 B

typedef int i32x4 __attribute__((ext_vector_type(4)));

__device__ __forceinline__ void llds16(const void* g, void* l) {
    __builtin_amdgcn_global_load_lds(
        (const __attribute__((address_space(1))) void*)g,
        (__attribute__((address_space(3))) void*)l,
        16, 0, 0);
}

__device__ __forceinline__ float f4max(float4 v) {
    return fmaxf(fmaxf(fabsf(v.x), fabsf(v.y)), fmaxf(fabsf(v.z), fabsf(v.w)));
}

__device__ __forceinline__ void barrier_f() {
    asm volatile("" ::: "memory");
    __builtin_amdgcn_s_barrier();
    asm volatile("" ::: "memory");
}

// ---------------- amax stage 1: per-block partial maxima (NO atomics) ----------------
__global__ __launch_bounds__(256) void k_amax(const float4* __restrict__ x,
                                              const float4* __restrict__ w4,
                                              float* __restrict__ part) {
    __shared__ float red[4];
    int t = threadIdx.x;
    float m = 0.f;
    if (blockIdx.x < 2048) {
        int tid = blockIdx.x * 256 + t;
        float4 v[16];
#pragma unroll
        for (int k = 0; k < 16; ++k)
            v[k] = x[(size_t)tid + (size_t)k * 524288];
#pragma unroll
        for (int k = 0; k < 16; ++k) m = fmaxf(m, f4max(v[k]));
    } else {
        int b = blockIdx.x - 2048;          // 0..1151
        int chunk = b / 288;
        int tid = (b - chunk * 288) * 256 + t;
        m = f4max(w4[(size_t)chunk * 73728 + tid]);
    }
    for (int off = 32; off > 0; off >>= 1) m = fmaxf(m, __shfl_xor(m, off, 64));
    if ((t & 63) == 0) red[t >> 6] = m;
    __syncthreads();
    if (t == 0)
        part[blockIdx.x] = fmaxf(fmaxf(red[0], red[1]), fmaxf(red[2], red[3]));
}

// ---------------- amax stage 2: reduce partials -> amaxb[0..4] ----------------
__global__ __launch_bounds__(256) void k_amax2(const float* __restrict__ part,
                                               unsigned* __restrict__ amaxb) {
    __shared__ float red[4];
    int t = threadIdx.x;
    float m = 0.f;
#pragma unroll
    for (int k = 0; k < 8; ++k) m = fmaxf(m, part[t + k * 256]);
    for (int off = 32; off > 0; off >>= 1) m = fmaxf(m, __shfl_xor(m, off, 64));
    if ((t & 63) == 0) red[t >> 6] = m;
    __syncthreads();
    if (t == 0)
        amaxb[0] = __float_as_uint(fmaxf(fmaxf(red[0], red[1]), fmaxf(red[2], red[3])));
    // w: one wave per chunk, 288 partials each
    int c = t >> 6, l = t & 63;
    float wm = 0.f;
#pragma unroll
    for (int k = 0; k < 5; ++k) {
        int i = l + k * 64;
        if (i < 288) wm = fmaxf(wm, part[2048 + c * 288 + i]);
    }
    for (int off = 32; off > 0; off >>= 1) wm = fmaxf(wm, __shfl_xor(wm, off, 64));
    if (l == 0) amaxb[1 + c] = __float_as_uint(wm);
}

// ---------------- quantize x : NCHW f32 -> NHWC int8 ----------------
__global__ __launch_bounds__(256) void k_quant_x(const float* __restrict__ x,
                                                 signed char* __restrict__ qx,
                                                 const unsigned* __restrict__ amaxb) {
    float inv = 127.0f / fmaxf(__uint_as_float(amaxb[0]), 1e-12f);
    int row = blockIdx.x;                 // n*128 + h
    int n = row >> 7, h = row & 127;
    int t = threadIdx.x;
    int w4 = t & 31, cg = t >> 5;         // w4: float4 slot along w; cg in [0,8)
    const float* base = x + (size_t)n * 256 * 16384 + (size_t)h * 128 + w4 * 4;
#pragma unroll
    for (int pp = 0; pp < 2; ++pp) {
        int c0 = pp * 128 + cg * 16;
        float4 v[16];
#pragma unroll
        for (int j = 0; j < 16; ++j)
            v[j] = *(const float4*)(base + (size_t)(c0 + j) * 16384);
#pragma unroll
        for (int i = 0; i < 4; ++i) {
            unsigned wds[4];
#pragma unroll
            for (int jg = 0; jg < 4; ++jg) {
                unsigned u = 0;
#pragma unroll
                for (int jj = 0; jj < 4; ++jj) {
                    float f = (&v[jg * 4 + jj].x)[i];
                    int q = (int)fminf(fmaxf(rintf(f * inv), -128.f), 127.f);
                    u |= ((unsigned)(q & 255)) << (8 * jj);
                }
                wds[jg] = u;
            }
            *(uint4*)&qx[(size_t)row * 32768 + (size_t)(w4 * 4 + i) * 256 + c0] =
                make_uint4(wds[0], wds[1], wds[2], wds[3]);
        }
    }
}

// ---------------- quantize w : OIHW f32 -> [rs][oc][c] int8 ----------------
__global__ void k_quant_w(const float* __restrict__ wsrc, signed char* __restrict__ qw,
                          const unsigned* __restrict__ amaxb) {
    int idx = blockIdx.x * 256 + threadIdx.x;   // 131072 = 512 blocks
    int oc = idx >> 8, c = idx & 255;
    float inv = 127.0f / fmaxf(__uint_as_float(amaxb[1 + (oc >> 7)]), 1e-12f);
    const float* src = wsrc + (size_t)idx * 9;
    float v[9];
#pragma unroll
    for (int rs = 0; rs < 9; ++rs) v[rs] = src[rs];
#pragma unroll
    for (int rs = 0; rs < 9; ++rs) {
        float qf = fminf(fmaxf(rintf(v[rs] * inv), -128.f), 127.f);
        qw[((size_t)(rs * 512 + oc)) * 256 + c] = (signed char)(int)qf;
    }
}

// ---------------- conv : implicit GEMM, T3/T4 counted-vmcnt pipeline ----------------
// Round-7: m201-class schedule. grid 1024 (XCD swizzle: each XCD owns image n),
// block 512 (8 waves), 1 block/CU. Block tile: 128oc x 4 output rows x 128px.
// Wave (rowsel=wid>>1, whalf=wid&1) = 128oc x 64px (8mf x 4nf 16x16x64 fragments).
// LDS (149 KB): xs dbuf 2x[6 rows][130 slots][64c] (slot=w+1; slots 0,129 = w-halo,
// pre-zeroed once, never staged -> staging is exactly 512 uniform loads/row) +
// wt dbuf 2x[3 s][128oc][64c]. 12 phases over (cb,r); per phase:
//   issue next-phase global_load_lds -> s_waitcnt vmcnt(N) COUNTED (never 0 mid-loop)
//   -> raw s_barrier -> ds_read frags + 96 MFMA (setprio 1) -> raw s_barrier.
// vmcnt ledger (per-wave insts: wt-stage=3, xs-stage=6, issue order wt-then-xs):
//   r0 -> N=3 (after wt_p: wt_{p+1}); r1/r2 with xs in flight -> N=9; p10 -> 3; p11 -> 0.
// Round-6's __syncthreads drained vmcnt(0) 12x/block -> LDS-read and MFMA pipes
// serialized (155us = 78us MFMA + ~70us LDS). This schedule overlaps them.
__global__ __launch_bounds__(512, 2) void k_conv(
    const signed char* __restrict__ qx, const signed char* __restrict__ qw,
    const signed char* __restrict__ zb, const unsigned* __restrict__ amaxb,
    const float* __restrict__ bias, float* __restrict__ out) {
    __shared__ __align__(16) signed char xs2[2 * 6 * 130 * 64];   // 99840 B
    __shared__ __align__(16) signed char wt2[2 * 3 * 128 * 64];   // 49152 B
    int orig = blockIdx.x;                      // 0..1023
    int wgid = (orig & 7) * 128 + (orig >> 3);  // bijective XCD swizzle
    int n = wgid >> 7;                          // image (== orig&7: one per XCD)
    int rq = (wgid >> 2) & 31, ocg = wgid & 3;  // row-quad, 128-oc group (= w chunk)
    int h0 = rq * 4;
    int t = threadIdx.x, wid = t >> 6, lane = t & 63;
    int lp = lane & 15, hi = lane >> 4;
    int rowsel = wid >> 1, whalf = wid & 1;

    i32x4 acc[8][4] = {};

    // ---- staging (all loads wave-uniform: exact vmcnt counting) ----
    auto stageX = [&](int cbx, int bufx) {     // 6 insts/wave
#pragma unroll
        for (int i = 0; i < 6; ++i) {
            int hh = h0 - 1 + i;
            int w = t >> 2, q4 = t & 3;
            int q4s = q4 ^ (((w + 1) >> 1) & 3);   // slot = w+1 read-swizzle inverse
            const signed char* src = (hh >= 0 && hh < 128)
                ? qx + (size_t)(n * 128 + hh) * 32768 + w * 256 + cbx * 64 + q4s * 16
                : zb;
            llds16(src, xs2 + (size_t)bufx * 49920 + i * 8320 + 64 + t * 16);
        }
    };
    auto stageW = [&](int cbw, int rw, int bufw) {  // 3 insts/wave
#pragma unroll
        for (int i = 0; i < 3; ++i) {
            int oc = t >> 2, q4 = t & 3;
            int q4s = q4 ^ ((oc >> 1) & 3);
            const signed char* src = qw
                + (size_t)((rw * 3 + i) * 512 + ocg * 128 + oc) * 256 + cbw * 64 + q4s * 16;
            llds16(src, wt2 + (size_t)bufw * 24576 + i * 8192 + t * 16);
        }
    };

    // ---- prologue: zero w-halo LDS slots (slots 0 and 129 of every row, both bufs) ----
    if (t < 96) {
        int unit = t >> 2, q = t & 3;
        int buf = unit / 12, rem = unit % 12;
        int rowk = rem >> 1, side = rem & 1;
        *(i32x4*)&xs2[(size_t)buf * 49920 + rowk * 8320 + (side ? 129 : 0) * 64 + q * 16] =
            i32x4{0, 0, 0, 0};
    }
    stageX(0, 0);
    stageW(0, 0, 0);
    asm volatile("s_waitcnt lgkmcnt(0)" ::: "memory");   // halo zeros done
    barrier_f();

    // ---- 12-phase pipelined K-loop ----
#pragma unroll
    for (int p = 0; p < 12; ++p) {
        const int r = p % 3, cb = p / 3;
        if (p < 11) stageW((p + 1) / 3, (p + 1) % 3, (p + 1) & 1);
        if (r == 1 && cb < 3) stageX(cb + 1, (cb + 1) & 1);
        // counted vmcnt: wait for this phase's buffers only; keep later stages in flight
        if (p == 11)      asm volatile("s_waitcnt vmcnt(0)" ::: "memory");
        else if (r == 0 || p == 10) asm volatile("s_waitcnt vmcnt(3)" ::: "memory");
        else              asm volatile("s_waitcnt vmcnt(9)" ::: "memory");
        barrier_f();                       // all waves' slices landed
        const int wb = p & 1, xb = cb & 1, rowk = r + rowsel;
#pragma unroll
        for (int s = 0; s < 3; ++s) {
            i32x4 a[8], b[4];
#pragma unroll
            for (int mf = 0; mf < 8; ++mf) {
                int ocr = mf * 16 + lp;
                a[mf] = *(const i32x4*)&wt2[(size_t)wb * 24576 + s * 8192 + ocr * 64
                                            + ((hi ^ ((ocr >> 1) & 3)) << 4)];
            }
#pragma unroll
            for (int nf = 0; nf < 4; ++nf) {
                int slot = whalf * 64 + nf * 16 + lp + s;   // = px + s  (w = px+s-1)
                b[nf] = *(const i32x4*)&xs2[(size_t)xb * 49920 + rowk * 8320 + slot * 64
                                            + ((hi ^ ((slot >> 1) & 3)) << 4)];
            }
            __builtin_amdgcn_s_setprio(1);
#pragma unroll
            for (int mf = 0; mf < 8; ++mf)
#pragma unroll
                for (int nf = 0; nf < 4; ++nf)
                    acc[mf][nf] = __builtin_amdgcn_mfma_i32_16x16x64_i8(
                        a[mf], b[nf], acc[mf][nf], 0, 0, 0);
            __builtin_amdgcn_s_setprio(0);
        }
        barrier_f();                       // all waves done reading -> bufs reusable
    }

    float sx = fmaxf(__uint_as_float(amaxb[0]), 1e-12f) / 127.0f;
    float sw = fmaxf(__uint_as_float(amaxb[1 + ocg]), 1e-12f) / 127.0f;
    float sc = sx * sw;
    int h = h0 + rowsel;
#pragma unroll
    for (int mf = 0; mf < 8; ++mf)
#pragma unroll
        for (int nf = 0; nf < 4; ++nf)
#pragma unroll
            for (int j = 0; j < 4; ++j) {
                int oc = ocg * 128 + mf * 16 + hi * 4 + j;
                int px = whalf * 64 + nf * 16 + lp;
                out[((size_t)(n * 512 + oc) * 128 + h) * 128 + px] =
                    (float)acc[mf][nf][j] * sc + bias[oc];
            }
}

extern "C" void kernel_launch(void* const* d_in, const int* in_sizes, int n_in,
                              void* d_out, int out_size, void* d_ws, size_t ws_size,
                              hipStream_t stream) {
    const float* x    = (const float*)d_in[0];
    const float* wgt  = (const float*)d_in[1];
    const float* bias = (const float*)d_in[2];
    float* out = (float*)d_out;

    unsigned* amaxb = (unsigned*)d_ws;
    float* part = (float*)((char*)d_ws + 256);
    signed char* qx = (signed char*)d_ws + 16384;
    signed char* qw = (signed char*)d_ws + 16384 + 33554432;
    const signed char* zb = (const signed char*)d_ws + 64;   // 16B zeros for OOB redirect

    hipMemsetAsync(d_ws, 0, 256, stream);   // zb zeros (amax slots overwritten by k_amax2)

    k_amax<<<3200, 256, 0, stream>>>((const float4*)x, (const float4*)wgt, part);
    k_amax2<<<1, 256, 0, stream>>>(part, amaxb);
    k_quant_x<<<1024, 256, 0, stream>>>(x, qx, amaxb);
    k_quant_w<<<512, 256, 0, stream>>>(wgt, qw, amaxb);
    k_conv<<<dim3(1024), 512, 0, stream>>>(qx, qw, zb, amaxb, bias, out);
}